// Round 5
// baseline (165.473 us; speedup 1.0000x reference)
//
#include <hip/hip_runtime.h>
#include <hip/hip_bf16.h>

#define B_  8
#define S_  4096
#define DM  1024
#define DO  1024

typedef __attribute__((ext_vector_type(4))) float f32x4;
typedef __attribute__((ext_vector_type(8))) short bf16x8;

__device__ inline unsigned int pkbf(float a, float b) {
    __hip_bfloat162 h = __float22bfloat162_rn(float2{a, b});
    union { __hip_bfloat162 h2; unsigned int u; } cv;
    cv.h2 = h;
    return cv.u;
}

// ---- prep: wpack[b][nb:8][kt:32] 8KB tiles: [col:128][g':4 x16B] bf16 ----
// 64-B rows (k=32 per col), 16B group g stored at slot g' = g ^ ((col>>1)&3).
// GEMM stages linearly via global_load_lds; frag reads apply the same XOR.
__global__ __launch_bounds__(256) void prep_wpack(
    const float* __restrict__ W, const int* __restrict__ sel_idx,
    const float* __restrict__ sel_probs, unsigned short* __restrict__ wpack)
{
    const int kt = blockIdx.x, nb = blockIdx.y, b = blockIdx.z;
    const int i0 = sel_idx[b*2+0], i1 = sel_idx[b*2+1];
    const float p0 = sel_probs[b*2+0], p1 = sel_probs[b*2+1];
    const int t = threadIdx.x;
    const int col = t & 127;               // col within nb-tile
    const int gh  = t >> 7;                // handles g = gh*2, gh*2+1

    const int o = nb * 128 + col;
    const float* w0 = W + (size_t)i0 * DM * DO + (size_t)(kt * 32) * DO + o;
    const float* w1 = W + (size_t)i1 * DM * DO + (size_t)(kt * 32) * DO + o;

    char* tile = (char*)wpack + ((size_t)((b * 8 + nb) * 32 + kt)) * 8192;
    const int q = (col >> 1) & 3;

    #pragma unroll
    for (int gg = 0; gg < 2; ++gg) {
        const int g = gh * 2 + gg;
        float v[8];
        #pragma unroll
        for (int j = 0; j < 8; ++j)
            v[j] = p0 * w0[(size_t)(g * 8 + j) * DO] + p1 * w1[(size_t)(g * 8 + j) * DO];
        uint4 u;
        u.x = pkbf(v[0], v[1]); u.y = pkbf(v[2], v[3]);
        u.z = pkbf(v[4], v[5]); u.w = pkbf(v[6], v[7]);
        *reinterpret_cast<uint4*>(tile + col * 64 + ((g ^ q) << 4)) = u;
    }
}

__global__ __launch_bounds__(256) void prep_beff(
    const float* __restrict__ bias, const int* __restrict__ sel_idx,
    const float* __restrict__ sel_probs, float* __restrict__ beff)
{
    const int b = blockIdx.x;
    const int i0 = sel_idx[b*2+0], i1 = sel_idx[b*2+1];
    const float p0 = sel_probs[b*2+0], p1 = sel_probs[b*2+1];
    for (int o = threadIdx.x; o < DO; o += blockDim.x)
        beff[(size_t)b * DO + o] = p0 * bias[(size_t)i0 * DO + o]
                                 + p1 * bias[(size_t)i1 * DO + o];
}

// ---- GEMM: 128x128 tile, BK=32, 4 waves (2x2 of 64x64), dbuf A+B = 32KB LDS.
// 128-reg class -> 4 blocks/CU (16 waves): TLP hides latency (m97/m114 regime). ----
__global__ __launch_bounds__(256, 4) void gemm4(
    const float* __restrict__ X, const unsigned short* __restrict__ wpack,
    const float* __restrict__ beff, float* __restrict__ out)
{
    __shared__ char lds[32768];   // A: 0 / 8192 ; B: 16384 / 24576

    const int id = blockIdx.x;
    const int swz = (id & 7) * 256 + (id >> 3);  // XCD-chunked, bijective (2048=8*256)
    const int b  = swz >> 8;                     // one batch per XCD
    const int bm = (swz >> 3) & 31;
    const int nb = swz & 7;                      // nb fastest: siblings share X rows

    const int t = threadIdx.x;
    const int wave = t >> 6, lane = t & 63;
    const int wm = wave >> 1, wn = wave & 1;     // 2x2 grid, 64x64 out per wave
    const int fr = lane & 15, fq = lane >> 4;

    // A staging: thread t -> row = t>>1, k-half h = t&1 (64B fp32 contiguous)
    const int s_row = t >> 1;
    const int s_h   = t & 1;
    const float* xrow = X + ((size_t)(b * S_ + bm * 128 + s_row)) * DM + s_h * 16;
    const int sq = (s_row >> 1) & 3;
    const int wrA0 = s_row * 64 + (((s_h * 2 + 0) ^ sq) << 4);
    const int wrA1 = s_row * 64 + (((s_h * 2 + 1) ^ sq) << 4);

    const char* wtile = (const char*)wpack + ((size_t)((b * 8 + nb) * 32)) * 8192;

    // frag read offsets (XOR term (fr>>1)&3 is thread-constant, folds into base)
    const int axor = (fr >> 1) & 3;
    const int rdA = (wm * 64 + fr) * 64 + ((fq ^ axor) << 4);   // + abuf + m*1024
    const int rdB = (wn * 64 + fr) * 64 + ((fq ^ axor) << 4);   // + 16384 + bbuf + nf*1024

    f32x4 acc[4][4] = {};
    float4 ax0, ax1, ax2, ax3;

#define LOAD_X(KT)                                                            \
    {   const float* s = xrow + (KT) * 32;                                    \
        ax0 = *reinterpret_cast<const float4*>(s);                            \
        ax1 = *reinterpret_cast<const float4*>(s + 4);                        \
        ax2 = *reinterpret_cast<const float4*>(s + 8);                        \
        ax3 = *reinterpret_cast<const float4*>(s + 12); }

#define STAGE_B(KT, BOFF)                                                     \
    {   const char* gB = wtile + (size_t)(KT) * 8192;                         \
        _Pragma("unroll")                                                     \
        for (int r = 0; r < 2; ++r)                                           \
            __builtin_amdgcn_global_load_lds(                                 \
                (const __attribute__((address_space(1))) void*)(gB + (wave*2+r)*1024 + lane*16), \
                (__attribute__((address_space(3))) void*)(lds + (BOFF) + (wave*2+r)*1024),       \
                16, 0, 0); }

#define WRITE_A(AOFF)                                                         \
    {   uint4 u0, u1;                                                         \
        u0.x = pkbf(ax0.x, ax0.y); u0.y = pkbf(ax0.z, ax0.w);                 \
        u0.z = pkbf(ax1.x, ax1.y); u0.w = pkbf(ax1.z, ax1.w);                 \
        u1.x = pkbf(ax2.x, ax2.y); u1.y = pkbf(ax2.z, ax2.w);                 \
        u1.z = pkbf(ax3.x, ax3.y); u1.w = pkbf(ax3.z, ax3.w);                 \
        *reinterpret_cast<uint4*>(lds + (AOFF) + wrA0) = u0;                  \
        *reinterpret_cast<uint4*>(lds + (AOFF) + wrA1) = u1; }

    // ---------- prologue: stage kt=0 into buf0 ----------
    LOAD_X(0);
    __builtin_amdgcn_sched_barrier(0);
    STAGE_B(0, 16384);
    __builtin_amdgcn_sched_barrier(0);
    WRITE_A(0);
    __syncthreads();

    // ---------- main loop: one barrier per K-step; cross-block TLP hides drains ----------
    for (int kt = 0; kt < 32; ++kt) {
        const int cur = (kt & 1) * 8192;
        const int nxt = 8192 - cur;

        if (kt < 31) {
            LOAD_X(kt + 1);
            __builtin_amdgcn_sched_barrier(0);
            STAGE_B(kt + 1, 16384 + nxt);
            __builtin_amdgcn_sched_barrier(0);
        }

        bf16x8 bf[4];
        #pragma unroll
        for (int nf = 0; nf < 4; ++nf)
            bf[nf] = *reinterpret_cast<const bf16x8*>(lds + 16384 + cur + rdB + nf * 1024);
        #pragma unroll
        for (int m = 0; m < 4; ++m) {
            bf16x8 af = *reinterpret_cast<const bf16x8*>(lds + cur + rdA + m * 1024);
            #pragma unroll
            for (int nf = 0; nf < 4; ++nf)
                acc[m][nf] = __builtin_amdgcn_mfma_f32_16x16x32_bf16(af, bf[nf], acc[m][nf], 0, 0, 0);
        }

        if (kt < 31) { WRITE_A(nxt); }   // ax consume: compiler-counted vmcnt
        __syncthreads();
    }

    // ---------- epilogue: bias + sigmoid, fp32 store ----------
    const float* be = beff + (size_t)b * DO + nb * 128 + wn * 64;
    float bv[4];
    #pragma unroll
    for (int nf = 0; nf < 4; ++nf) bv[nf] = be[nf * 16 + fr];

    float* ob = out + ((size_t)(b * S_ + bm * 128 + wm * 64)) * DO + nb * 128 + wn * 64;
    #pragma unroll
    for (int m = 0; m < 4; ++m) {
        #pragma unroll
        for (int nf = 0; nf < 4; ++nf) {
            const int col = nf * 16 + fr;
            #pragma unroll
            for (int r = 0; r < 4; ++r) {
                const int row = m * 16 + fq * 4 + r;
                const float xv = acc[m][nf][r] + bv[nf];
                ob[(size_t)row * DO + col] = 1.0f / (1.0f + __expf(-xv));
            }
        }
    }
#undef LOAD_X
#undef STAGE_B
#undef WRITE_A
}

extern "C" void kernel_launch(void* const* d_in, const int* in_sizes, int n_in,
                              void* d_out, int out_size, void* d_ws, size_t ws_size,
                              hipStream_t stream) {
    const float* tensor    = (const float*)d_in[0];
    const int*   sel_idx   = (const int*)d_in[1];
    const float* sel_probs = (const float*)d_in[2];
    const float* W         = (const float*)d_in[3];
    const float* bias      = (const float*)d_in[4];
    float* out = (float*)d_out;

    unsigned short* wpack = (unsigned short*)d_ws;                       // 16 MiB
    float* beff = (float*)((char*)d_ws + (size_t)8 * 8 * 32 * 8192);     // +32 KiB

    hipLaunchKernelGGL(prep_wpack, dim3(32, 8, 8), dim3(256), 0, stream,
                       W, sel_idx, sel_probs, wpack);
    hipLaunchKernelGGL(prep_beff, dim3(8), dim3(256), 0, stream,
                       bias, sel_idx, sel_probs, beff);
    hipLaunchKernelGGL(gemm4, dim3(2048), dim3(256), 0, stream,
                       tensor, wpack, beff, out);
}

// Round 6
// 157.851 us; speedup vs baseline: 1.0483x; 1.0483x over previous
//
#include <hip/hip_runtime.h>
#include <hip/hip_bf16.h>

#define B_  8
#define S_  4096
#define DM  1024
#define DO  1024

typedef __attribute__((ext_vector_type(4))) float f32x4;
typedef __attribute__((ext_vector_type(8))) short bf16x8;

__device__ inline unsigned int pkbf(float a, float b) {
    __hip_bfloat162 h = __float22bfloat162_rn(float2{a, b});
    union { __hip_bfloat162 h2; unsigned int u; } cv;
    cv.h2 = h;
    return cv.u;
}

// ================= fast path: pre-tiled bf16 operands =================
// Tile format (32 KB, shared by xpack/wpack): [row:256][128 B], the 16-byte
// k-group g of row r stored at byte r*128 + ((g ^ (r&7))<<4). This IS the LDS
// image: GEMM stages it linearly via global_load_lds (rule 21).

__global__ __launch_bounds__(256) void prep_xpack(
    const float* __restrict__ X, unsigned short* __restrict__ xpack)
{
    const int kt = blockIdx.x, bm = blockIdx.y, b = blockIdx.z;
    const int r = threadIdx.x;
    const float* src = X + ((size_t)(b * S_ + bm * 256 + r)) * DM + kt * 64;
    char* dst = (char*)xpack + ((size_t)((b * 16 + bm) * 16 + kt)) * 32768 + r * 128;
    const int rx = r & 7;
    #pragma unroll
    for (int g = 0; g < 8; ++g) {
        float4 a = *reinterpret_cast<const float4*>(src + g * 8);
        float4 c = *reinterpret_cast<const float4*>(src + g * 8 + 4);
        uint4 u;
        u.x = pkbf(a.x, a.y); u.y = pkbf(a.z, a.w);
        u.z = pkbf(c.x, c.y); u.w = pkbf(c.z, c.w);
        *reinterpret_cast<uint4*>(dst + ((g ^ rx) << 4)) = u;
    }
}

__global__ __launch_bounds__(256) void prep_wpack64(
    const float* __restrict__ W, const int* __restrict__ sel_idx,
    const float* __restrict__ sel_probs, unsigned short* __restrict__ wpack)
{
    const int kt = blockIdx.x, nb = blockIdx.y, b = blockIdx.z;
    const int i0 = sel_idx[b*2+0], i1 = sel_idx[b*2+1];
    const float p0 = sel_probs[b*2+0], p1 = sel_probs[b*2+1];
    const int c = threadIdx.x;                 // output col within 256-tile
    const int o = nb * 256 + c;
    const float* w0 = W + (size_t)i0 * DM * DO + (size_t)(kt * 64) * DO + o;
    const float* w1 = W + (size_t)i1 * DM * DO + (size_t)(kt * 64) * DO + o;
    char* dst = (char*)wpack + ((size_t)((b * 4 + nb) * 16 + kt)) * 32768 + c * 128;
    const int cx = c & 7;
    #pragma unroll
    for (int g = 0; g < 8; ++g) {
        float v[8];
        #pragma unroll
        for (int j = 0; j < 8; ++j)
            v[j] = p0 * w0[(size_t)(g * 8 + j) * DO] + p1 * w1[(size_t)(g * 8 + j) * DO];
        uint4 u;
        u.x = pkbf(v[0], v[1]); u.y = pkbf(v[2], v[3]);
        u.z = pkbf(v[4], v[5]); u.w = pkbf(v[6], v[7]);
        *reinterpret_cast<uint4*>(dst + ((g ^ cx) << 4)) = u;
    }
}

__global__ __launch_bounds__(256) void prep_beff(
    const float* __restrict__ bias, const int* __restrict__ sel_idx,
    const float* __restrict__ sel_probs, float* __restrict__ beff)
{
    const int b = blockIdx.x;
    const int i0 = sel_idx[b*2+0], i1 = sel_idx[b*2+1];
    const float p0 = sel_probs[b*2+0], p1 = sel_probs[b*2+1];
    for (int o = threadIdx.x; o < DO; o += blockDim.x)
        beff[(size_t)b * DO + o] = p0 * bias[(size_t)i0 * DO + o]
                                 + p1 * bias[(size_t)i1 * DO + o];
}

// ---- GEMM: 256x256, BK=64, 8 waves (2Mx4N), dbuf 128KB, m201-style 4 phases
// per K-tile, both operands via global_load_lds, one vmcnt(0)/tile (3-ph cover).
__global__ __launch_bounds__(512, 2) void gemmx(
    const unsigned short* __restrict__ xpack, const unsigned short* __restrict__ wpack,
    const float* __restrict__ beff, float* __restrict__ out)
{
    extern __shared__ char lds[];   // A: 0/32K ; B: 64K/96K

    const int id = blockIdx.x;
    const int swz = (id & 7) * 64 + (id >> 3);  // XCD-chunked, bijective (512=8*64)
    const int b  = swz >> 6;
    const int bm = (swz >> 2) & 15;
    const int nb = swz & 3;

    const int t = threadIdx.x;
    const int wave = t >> 6, lane = t & 63;
    const int wm = wave >> 2, wnw = wave & 3;   // 2x4 grid, 128x64 out per wave
    const int fr = lane & 15, fq = lane >> 4;

    const char* xt = (const char*)xpack + ((size_t)((b * 16 + bm) * 16)) * 32768;
    const char* wt = (const char*)wpack + ((size_t)((b * 4 + nb) * 16)) * 32768;

    const int s0 = ((fq ^ (fr & 7)) << 4);          // ks=0 slot
    const int s1 = (((4 + fq) ^ (fr & 7)) << 4);    // ks=1 slot
    const int rdA = wm * 16384 + fr * 128;          // + m*2048 + s
    const int rdB = wnw * 8192 + fr * 128;          // + nf*2048 + s

    f32x4 acc[8][4] = {};

#define GLOAD(SRC, DSTOFF, I)                                                 \
    __builtin_amdgcn_global_load_lds(                                         \
        (const __attribute__((address_space(1))) void*)((SRC) + wave*4096 + (I)*1024 + lane*16), \
        (__attribute__((address_space(3))) void*)(lds + (DSTOFF) + wave*4096 + (I)*1024), 16, 0, 0)

#define MFMA16(MB, AF, BK)                                                    \
    __builtin_amdgcn_s_setprio(1);                                            \
    _Pragma("unroll")                                                         \
    for (int m = 0; m < 4; ++m) {                                             \
        _Pragma("unroll")                                                     \
        for (int nf = 0; nf < 4; ++nf)                                        \
            acc[(MB)+m][nf] = __builtin_amdgcn_mfma_f32_16x16x32_bf16(        \
                AF[m], BK[nf], acc[(MB)+m][nf], 0, 0, 0);                     \
    }                                                                         \
    __builtin_amdgcn_s_setprio(0);

    // ---------- prologue: stage tile 0 into buf0 ----------
    #pragma unroll
    for (int i = 0; i < 4; ++i) { GLOAD(xt, 0, i); GLOAD(wt, 65536, i); }
    asm volatile("s_waitcnt vmcnt(0)" ::: "memory");
    __builtin_amdgcn_s_barrier();

    #pragma unroll 1
    for (int kt = 0; kt < 16; ++kt) {
        const int ca = (kt & 1) * 32768;
        const int cb = 65536 + ca;
        const int na = 32768 - ca;
        const int nbf = 65536 + na;
        const char* gxn = xt + (size_t)(kt + 1) * 32768;
        const char* gwn = wt + (size_t)(kt + 1) * 32768;

        bf16x8 bk[4], af[4];

        // ---- p0: B(ks0)+A(m0-3,ks0) reads; issue all 8 next-tile gloads ----
        #pragma unroll
        for (int nf = 0; nf < 4; ++nf)
            bk[nf] = *reinterpret_cast<const bf16x8*>(lds + cb + rdB + nf*2048 + s0);
        #pragma unroll
        for (int m = 0; m < 4; ++m)
            af[m] = *reinterpret_cast<const bf16x8*>(lds + ca + rdA + m*2048 + s0);
        __builtin_amdgcn_sched_barrier(0);
        if (kt < 15) {
            #pragma unroll
            for (int i = 0; i < 4; ++i) { GLOAD(gxn, na, i); GLOAD(gwn, nbf, i); }
        }
        __builtin_amdgcn_sched_barrier(0);
        __builtin_amdgcn_s_barrier();
        asm volatile("s_waitcnt lgkmcnt(0)" ::: "memory");
        __builtin_amdgcn_sched_barrier(0);
        MFMA16(0, af, bk)
        __builtin_amdgcn_sched_barrier(0);
        __builtin_amdgcn_s_barrier();

        // ---- p1: A(m4-7, ks0) ----
        #pragma unroll
        for (int m = 0; m < 4; ++m)
            af[m] = *reinterpret_cast<const bf16x8*>(lds + ca + rdA + (4+m)*2048 + s0);
        __builtin_amdgcn_sched_barrier(0);
        __builtin_amdgcn_s_barrier();
        asm volatile("s_waitcnt lgkmcnt(0)" ::: "memory");
        __builtin_amdgcn_sched_barrier(0);
        MFMA16(4, af, bk)
        __builtin_amdgcn_sched_barrier(0);
        __builtin_amdgcn_s_barrier();

        // ---- p2: B(ks1)+A(m0-3, ks1) ----
        #pragma unroll
        for (int nf = 0; nf < 4; ++nf)
            bk[nf] = *reinterpret_cast<const bf16x8*>(lds + cb + rdB + nf*2048 + s1);
        #pragma unroll
        for (int m = 0; m < 4; ++m)
            af[m] = *reinterpret_cast<const bf16x8*>(lds + ca + rdA + m*2048 + s1);
        __builtin_amdgcn_sched_barrier(0);
        __builtin_amdgcn_s_barrier();
        asm volatile("s_waitcnt lgkmcnt(0)" ::: "memory");
        __builtin_amdgcn_sched_barrier(0);
        MFMA16(0, af, bk)
        __builtin_amdgcn_sched_barrier(0);
        __builtin_amdgcn_s_barrier();

        // ---- p3: A(m4-7, ks1); drain next-tile stage (≈3 phases of cover) ----
        #pragma unroll
        for (int m = 0; m < 4; ++m)
            af[m] = *reinterpret_cast<const bf16x8*>(lds + ca + rdA + (4+m)*2048 + s1);
        __builtin_amdgcn_sched_barrier(0);
        __builtin_amdgcn_s_barrier();
        asm volatile("s_waitcnt lgkmcnt(0)" ::: "memory");
        __builtin_amdgcn_sched_barrier(0);
        MFMA16(4, af, bk)
        __builtin_amdgcn_sched_barrier(0);
        if (kt < 15) { asm volatile("s_waitcnt vmcnt(0)" ::: "memory"); }
        __builtin_amdgcn_s_barrier();
    }

    // ---------- epilogue: bias + sigmoid, fp32 store ----------
    const float* be = beff + (size_t)b * DO + nb * 256 + wnw * 64;
    float bv[4];
    #pragma unroll
    for (int nf = 0; nf < 4; ++nf) bv[nf] = be[nf * 16 + fr];

    float* ob = out + ((size_t)(b * S_ + bm * 256 + wm * 128)) * DO + nb * 256 + wnw * 64;
    #pragma unroll
    for (int mf = 0; mf < 8; ++mf) {
        #pragma unroll
        for (int nf = 0; nf < 4; ++nf) {
            const int col = nf * 16 + fr;
            #pragma unroll
            for (int r = 0; r < 4; ++r) {
                const int row = mf * 16 + fq * 4 + r;
                const float xv = acc[mf][nf][r] + bv[nf];
                ob[(size_t)row * DO + col] = 1.0f / (1.0f + __expf(-xv));
            }
        }
    }
#undef GLOAD
#undef MFMA16
}

// ================= fallback path (round-5, known-pass) =================
__global__ __launch_bounds__(256) void prep_wpack_f(
    const float* __restrict__ W, const int* __restrict__ sel_idx,
    const float* __restrict__ sel_probs, unsigned short* __restrict__ wpack)
{
    const int kt = blockIdx.x, nb = blockIdx.y, b = blockIdx.z;
    const int i0 = sel_idx[b*2+0], i1 = sel_idx[b*2+1];
    const float p0 = sel_probs[b*2+0], p1 = sel_probs[b*2+1];
    const int t = threadIdx.x;
    const int col = t & 127;
    const int gh  = t >> 7;
    const int o = nb * 128 + col;
    const float* w0 = W + (size_t)i0 * DM * DO + (size_t)(kt * 32) * DO + o;
    const float* w1 = W + (size_t)i1 * DM * DO + (size_t)(kt * 32) * DO + o;
    char* tile = (char*)wpack + ((size_t)((b * 8 + nb) * 32 + kt)) * 8192;
    const int q = (col >> 1) & 3;
    #pragma unroll
    for (int gg = 0; gg < 2; ++gg) {
        const int g = gh * 2 + gg;
        float v[8];
        #pragma unroll
        for (int j = 0; j < 8; ++j)
            v[j] = p0 * w0[(size_t)(g * 8 + j) * DO] + p1 * w1[(size_t)(g * 8 + j) * DO];
        uint4 u;
        u.x = pkbf(v[0], v[1]); u.y = pkbf(v[2], v[3]);
        u.z = pkbf(v[4], v[5]); u.w = pkbf(v[6], v[7]);
        *reinterpret_cast<uint4*>(tile + col * 64 + ((g ^ q) << 4)) = u;
    }
}

__global__ __launch_bounds__(256, 4) void gemm4(
    const float* __restrict__ X, const unsigned short* __restrict__ wpack,
    const float* __restrict__ beff, float* __restrict__ out)
{
    __shared__ char lds[32768];
    const int id = blockIdx.x;
    const int swz = (id & 7) * 256 + (id >> 3);
    const int b  = swz >> 8;
    const int bm = (swz >> 3) & 31;
    const int nb = swz & 7;
    const int t = threadIdx.x;
    const int wave = t >> 6, lane = t & 63;
    const int wm = wave >> 1, wn = wave & 1;
    const int fr = lane & 15, fq = lane >> 4;
    const int s_row = t >> 1;
    const int s_h   = t & 1;
    const float* xrow = X + ((size_t)(b * S_ + bm * 128 + s_row)) * DM + s_h * 16;
    const int sq = (s_row >> 1) & 3;
    const int wrA0 = s_row * 64 + (((s_h * 2 + 0) ^ sq) << 4);
    const int wrA1 = s_row * 64 + (((s_h * 2 + 1) ^ sq) << 4);
    const char* wtile = (const char*)wpack + ((size_t)((b * 8 + nb) * 32)) * 8192;
    const int axor = (fr >> 1) & 3;
    const int rdA = (wm * 64 + fr) * 64 + ((fq ^ axor) << 4);
    const int rdB = (wn * 64 + fr) * 64 + ((fq ^ axor) << 4);
    f32x4 acc[4][4] = {};
    float4 ax0, ax1, ax2, ax3;
#define LOAD_X(KT)                                                            \
    {   const float* s = xrow + (KT) * 32;                                    \
        ax0 = *reinterpret_cast<const float4*>(s);                            \
        ax1 = *reinterpret_cast<const float4*>(s + 4);                        \
        ax2 = *reinterpret_cast<const float4*>(s + 8);                        \
        ax3 = *reinterpret_cast<const float4*>(s + 12); }
#define STAGE_B(KT, BOFF)                                                     \
    {   const char* gB = wtile + (size_t)(KT) * 8192;                         \
        _Pragma("unroll")                                                     \
        for (int r = 0; r < 2; ++r)                                           \
            __builtin_amdgcn_global_load_lds(                                 \
                (const __attribute__((address_space(1))) void*)(gB + (wave*2+r)*1024 + lane*16), \
                (__attribute__((address_space(3))) void*)(lds + (BOFF) + (wave*2+r)*1024),       \
                16, 0, 0); }
#define WRITE_A(AOFF)                                                         \
    {   uint4 u0, u1;                                                         \
        u0.x = pkbf(ax0.x, ax0.y); u0.y = pkbf(ax0.z, ax0.w);                 \
        u0.z = pkbf(ax1.x, ax1.y); u0.w = pkbf(ax1.z, ax1.w);                 \
        u1.x = pkbf(ax2.x, ax2.y); u1.y = pkbf(ax2.z, ax2.w);                 \
        u1.z = pkbf(ax3.x, ax3.y); u1.w = pkbf(ax3.z, ax3.w);                 \
        *reinterpret_cast<uint4*>(lds + (AOFF) + wrA0) = u0;                  \
        *reinterpret_cast<uint4*>(lds + (AOFF) + wrA1) = u1; }
    LOAD_X(0);
    __builtin_amdgcn_sched_barrier(0);
    STAGE_B(0, 16384);
    __builtin_amdgcn_sched_barrier(0);
    WRITE_A(0);
    __syncthreads();
    for (int kt = 0; kt < 32; ++kt) {
        const int cur = (kt & 1) * 8192;
        const int nxt = 8192 - cur;
        if (kt < 31) {
            LOAD_X(kt + 1);
            __builtin_amdgcn_sched_barrier(0);
            STAGE_B(kt + 1, 16384 + nxt);
            __builtin_amdgcn_sched_barrier(0);
        }
        bf16x8 bf[4];
        #pragma unroll
        for (int nf = 0; nf < 4; ++nf)
            bf[nf] = *reinterpret_cast<const bf16x8*>(lds + 16384 + cur + rdB + nf * 1024);
        #pragma unroll
        for (int m = 0; m < 4; ++m) {
            bf16x8 af = *reinterpret_cast<const bf16x8*>(lds + cur + rdA + m * 1024);
            #pragma unroll
            for (int nf = 0; nf < 4; ++nf)
                acc[m][nf] = __builtin_amdgcn_mfma_f32_16x16x32_bf16(af, bf[nf], acc[m][nf], 0, 0, 0);
        }
        if (kt < 31) { WRITE_A(nxt); }
        __syncthreads();
    }
    const float* be = beff + (size_t)b * DO + nb * 128 + wn * 64;
    float bv[4];
    #pragma unroll
    for (int nf = 0; nf < 4; ++nf) bv[nf] = be[nf * 16 + fr];
    float* ob = out + ((size_t)(b * S_ + bm * 128 + wm * 64)) * DO + nb * 128 + wn * 64;
    #pragma unroll
    for (int m = 0; m < 4; ++m) {
        #pragma unroll
        for (int nf = 0; nf < 4; ++nf) {
            const int col = nf * 16 + fr;
            #pragma unroll
            for (int r = 0; r < 4; ++r) {
                const int row = m * 16 + fq * 4 + r;
                const float xv = acc[m][nf][r] + bv[nf];
                ob[(size_t)row * DO + col] = 1.0f / (1.0f + __expf(-xv));
            }
        }
    }
#undef LOAD_X
#undef STAGE_B
#undef WRITE_A
}

extern "C" void kernel_launch(void* const* d_in, const int* in_sizes, int n_in,
                              void* d_out, int out_size, void* d_ws, size_t ws_size,
                              hipStream_t stream) {
    const float* tensor    = (const float*)d_in[0];
    const int*   sel_idx   = (const int*)d_in[1];
    const float* sel_probs = (const float*)d_in[2];
    const float* W         = (const float*)d_in[3];
    const float* bias      = (const float*)d_in[4];
    float* out = (float*)d_out;

    const size_t XP = (size_t)2048 * 32768;          // 64 MiB xpack
    const size_t WP = (size_t)512 * 32768;           // 16 MiB wpack64
    const size_t NEED = XP + WP + (size_t)B_ * DO * 4;

    if (ws_size >= NEED) {
        unsigned short* xpack = (unsigned short*)d_ws;
        unsigned short* wpack = (unsigned short*)((char*)d_ws + XP);
        float* beff = (float*)((char*)d_ws + XP + WP);

        hipFuncSetAttribute((const void*)gemmx,
                            hipFuncAttributeMaxDynamicSharedMemorySize, 131072);

        hipLaunchKernelGGL(prep_xpack, dim3(16, 16, 8), dim3(256), 0, stream,
                           tensor, xpack);
        hipLaunchKernelGGL(prep_wpack64, dim3(16, 4, 8), dim3(256), 0, stream,
                           W, sel_idx, sel_probs, wpack);
        hipLaunchKernelGGL(prep_beff, dim3(8), dim3(256), 0, stream,
                           bias, sel_idx, sel_probs, beff);
        hipLaunchKernelGGL(gemmx, dim3(512), dim3(512), 131072, stream,
                           xpack, wpack, beff, out);
    } else {
        unsigned short* wpack = (unsigned short*)d_ws;                   // 16 MiB
        float* beff = (float*)((char*)d_ws + (size_t)8 * 8 * 32 * 8192);
        hipLaunchKernelGGL(prep_wpack_f, dim3(32, 8, 8), dim3(256), 0, stream,
                           W, sel_idx, sel_probs, wpack);
        hipLaunchKernelGGL(prep_beff, dim3(8), dim3(256), 0, stream,
                           bias, sel_idx, sel_probs, beff);
        hipLaunchKernelGGL(gemm4, dim3(2048), dim3(256), 0, stream,
                           tensor, wpack, beff, out);
    }
}

// Round 7
// 150.697 us; speedup vs baseline: 1.0980x; 1.0475x over previous
//
#include <hip/hip_runtime.h>
#include <hip/hip_bf16.h>

#define B_  8
#define S_  4096
#define DM  1024
#define DO  1024

typedef __attribute__((ext_vector_type(4))) float f32x4;
typedef __attribute__((ext_vector_type(8))) short bf16x8;

__device__ inline unsigned int pkbf(float a, float b) {
    __hip_bfloat162 h = __float22bfloat162_rn(float2{a, b});
    union { __hip_bfloat162 h2; unsigned int u; } cv;
    cv.h2 = h;
    return cv.u;
}

// ================= fast path: pre-tiled bf16 operands =================
// Tile format (32 KB): [row:256][128 B], 16-byte k-group g of row r stored at
// byte r*128 + ((g ^ (r&7))<<4). This IS the LDS image (rule 21).

__global__ __launch_bounds__(256) void prep_xpack(
    const float* __restrict__ X, unsigned short* __restrict__ xpack)
{
    const int kt = blockIdx.x, bm = blockIdx.y, b = blockIdx.z;
    const int r = threadIdx.x;
    const float* src = X + ((size_t)(b * S_ + bm * 256 + r)) * DM + kt * 64;
    char* dst = (char*)xpack + ((size_t)((b * 16 + bm) * 16 + kt)) * 32768 + r * 128;
    const int rx = r & 7;
    #pragma unroll
    for (int g = 0; g < 8; ++g) {
        float4 a = *reinterpret_cast<const float4*>(src + g * 8);
        float4 c = *reinterpret_cast<const float4*>(src + g * 8 + 4);
        uint4 u;
        u.x = pkbf(a.x, a.y); u.y = pkbf(a.z, a.w);
        u.z = pkbf(c.x, c.y); u.w = pkbf(c.z, c.w);
        *reinterpret_cast<uint4*>(dst + ((g ^ rx) << 4)) = u;
    }
}

__global__ __launch_bounds__(256) void prep_wpack64(
    const float* __restrict__ W, const int* __restrict__ sel_idx,
    const float* __restrict__ sel_probs, unsigned short* __restrict__ wpack)
{
    const int kt = blockIdx.x, nb = blockIdx.y, b = blockIdx.z;
    const int i0 = sel_idx[b*2+0], i1 = sel_idx[b*2+1];
    const float p0 = sel_probs[b*2+0], p1 = sel_probs[b*2+1];
    const int c = threadIdx.x;
    const int o = nb * 256 + c;
    const float* w0 = W + (size_t)i0 * DM * DO + (size_t)(kt * 64) * DO + o;
    const float* w1 = W + (size_t)i1 * DM * DO + (size_t)(kt * 64) * DO + o;
    char* dst = (char*)wpack + ((size_t)((b * 4 + nb) * 16 + kt)) * 32768 + c * 128;
    const int cx = c & 7;
    #pragma unroll
    for (int g = 0; g < 8; ++g) {
        float v[8];
        #pragma unroll
        for (int j = 0; j < 8; ++j)
            v[j] = p0 * w0[(size_t)(g * 8 + j) * DO] + p1 * w1[(size_t)(g * 8 + j) * DO];
        uint4 u;
        u.x = pkbf(v[0], v[1]); u.y = pkbf(v[2], v[3]);
        u.z = pkbf(v[4], v[5]); u.w = pkbf(v[6], v[7]);
        *reinterpret_cast<uint4*>(dst + ((g ^ cx) << 4)) = u;
    }
}

__global__ __launch_bounds__(256) void prep_beff(
    const float* __restrict__ bias, const int* __restrict__ sel_idx,
    const float* __restrict__ sel_probs, float* __restrict__ beff)
{
    const int b = blockIdx.x;
    const int i0 = sel_idx[b*2+0], i1 = sel_idx[b*2+1];
    const float p0 = sel_probs[b*2+0], p1 = sel_probs[b*2+1];
    for (int o = threadIdx.x; o < DO; o += blockDim.x)
        beff[(size_t)b * DO + o] = p0 * bias[(size_t)i0 * DO + o]
                                 + p1 * bias[(size_t)i1 * DO + o];
}

// ---- GEMM: 256x256, BK=64, 8 waves (2Mx4N), dbuf 128KB. ONE barrier + ONE
// vmcnt(0) per K-tile; fragment clusters register-pipelined so ds_reads flow
// under MFMA (compiler-counted lgkm); zero VALU in loop. ----
__global__ __launch_bounds__(512, 1) void gemmx(
    const unsigned short* __restrict__ xpack, const unsigned short* __restrict__ wpack,
    const float* __restrict__ beff, float* __restrict__ out)
{
    extern __shared__ char lds[];   // A: 0/32K ; B: 64K/96K

    const int id = blockIdx.x;
    const int swz = (id & 7) * 64 + (id >> 3);  // XCD-chunked, bijective (512=8*64)
    const int b  = swz >> 6;
    const int bm = (swz >> 2) & 15;
    const int nb = swz & 3;

    const int t = threadIdx.x;
    const int wave = t >> 6, lane = t & 63;
    const int wm = wave >> 2, wnw = wave & 3;   // 2x4 grid, 128x64 out per wave
    const int fr = lane & 15, fq = lane >> 4;

    const char* xt = (const char*)xpack + ((size_t)((b * 16 + bm) * 16)) * 32768;
    const char* wt = (const char*)wpack + ((size_t)((b * 4 + nb) * 16)) * 32768;

    const int s0 = ((fq ^ (fr & 7)) << 4);          // ks=0 slot
    const int s1 = (((4 + fq) ^ (fr & 7)) << 4);    // ks=1 slot
    const int rdA = wm * 16384 + fr * 128;          // + m*2048 + s
    const int rdB = wnw * 8192 + fr * 128;          // + nf*2048 + s

    f32x4 acc[8][4] = {};
    bf16x8 afA[4], afB[4], afC[4], afD[4], bkA[4], bkB[4];

#define GLOAD(SRC, DSTOFF, I)                                                 \
    __builtin_amdgcn_global_load_lds(                                         \
        (const __attribute__((address_space(1))) void*)((SRC) + wave*4096 + (I)*1024 + lane*16), \
        (__attribute__((address_space(3))) void*)(lds + (DSTOFF) + wave*4096 + (I)*1024), 16, 0, 0)

#define MFMA16(MB, AF, BK)                                                    \
    __builtin_amdgcn_s_setprio(1);                                            \
    _Pragma("unroll")                                                         \
    for (int m = 0; m < 4; ++m) {                                             \
        _Pragma("unroll")                                                     \
        for (int nf = 0; nf < 4; ++nf)                                        \
            acc[(MB)+m][nf] = __builtin_amdgcn_mfma_f32_16x16x32_bf16(        \
                AF[m], BK[nf], acc[(MB)+m][nf], 0, 0, 0);                     \
    }                                                                         \
    __builtin_amdgcn_s_setprio(0);

#define READ_A(DST, BUF, MB, SK)                                              \
    _Pragma("unroll")                                                         \
    for (int m = 0; m < 4; ++m)                                               \
        DST[m] = *reinterpret_cast<const bf16x8*>(lds + (BUF) + rdA + ((MB)+m)*2048 + (SK));

#define READ_B(DST, BUF, SK)                                                  \
    _Pragma("unroll")                                                         \
    for (int nf = 0; nf < 4; ++nf)                                            \
        DST[nf] = *reinterpret_cast<const bf16x8*>(lds + (BUF) + rdB + nf*2048 + (SK));

    // ---------- prologue: stage tile 0 into buf0 ----------
    #pragma unroll
    for (int i = 0; i < 4; ++i) { GLOAD(xt, 0, i); GLOAD(wt, 65536, i); }
    asm volatile("s_waitcnt vmcnt(0)" ::: "memory");
    __builtin_amdgcn_s_barrier();
    READ_A(afA, 0, 0, s0);
    READ_B(bkA, 65536, s0);

    #pragma unroll 1
    for (int kt = 0; kt < 16; ++kt) {
        const int ca  = (kt & 1) * 32768;
        const int cb  = 65536 + ca;
        const int na  = 32768 - ca;
        const int nbf = 65536 + na;

        // head: issue next-tile staging (drained at this tile's end)
        if (kt < 15) {
            const char* gxn = xt + (size_t)(kt + 1) * 32768;
            const char* gwn = wt + (size_t)(kt + 1) * 32768;
            #pragma unroll
            for (int i = 0; i < 4; ++i) { GLOAD(gxn, na, i); GLOAD(gwn, nbf, i); }
        }

        // register-pipelined clusters: reads for p+1 before MFMA p;
        // compiler inserts counted lgkm waits -> LDS flows under MFMA.
        READ_A(afB, ca, 4, s0);
        MFMA16(0, afA, bkA)

        READ_B(bkB, cb, s1);
        READ_A(afC, ca, 0, s1);
        MFMA16(4, afB, bkA)

        READ_A(afD, ca, 4, s1);
        MFMA16(0, afC, bkB)

        // close the tile: all our ds_reads of ca/cb must COMPLETE before the
        // barrier (next iter's gloads overwrite ca/cb); then drain staging.
        asm volatile("s_waitcnt lgkmcnt(0)" ::: "memory");
        if (kt < 15) { asm volatile("s_waitcnt vmcnt(0)" ::: "memory"); }
        __builtin_amdgcn_s_barrier();

        // post-barrier: next tile's first clusters; covered by reg-resident MFMA
        if (kt < 15) {
            READ_A(afA, na, 0, s0);
            READ_B(bkA, nbf, s0);
        }
        MFMA16(4, afD, bkB)
    }

    // ---------- epilogue: bias + sigmoid, fp32 store ----------
    const float* be = beff + (size_t)b * DO + nb * 256 + wnw * 64;
    float bv[4];
    #pragma unroll
    for (int nf = 0; nf < 4; ++nf) bv[nf] = be[nf * 16 + fr];

    float* ob = out + ((size_t)(b * S_ + bm * 256 + wm * 128)) * DO + nb * 256 + wnw * 64;
    #pragma unroll
    for (int mf = 0; mf < 8; ++mf) {
        #pragma unroll
        for (int nf = 0; nf < 4; ++nf) {
            const int col = nf * 16 + fr;
            #pragma unroll
            for (int r = 0; r < 4; ++r) {
                const int row = mf * 16 + fq * 4 + r;
                const float xv = acc[mf][nf][r] + bv[nf];
                ob[(size_t)row * DO + col] = 1.0f / (1.0f + __expf(-xv));
            }
        }
    }
#undef GLOAD
#undef MFMA16
#undef READ_A
#undef READ_B
}

// ================= fallback path (round-5, known-pass) =================
__global__ __launch_bounds__(256) void prep_wpack_f(
    const float* __restrict__ W, const int* __restrict__ sel_idx,
    const float* __restrict__ sel_probs, unsigned short* __restrict__ wpack)
{
    const int kt = blockIdx.x, nb = blockIdx.y, b = blockIdx.z;
    const int i0 = sel_idx[b*2+0], i1 = sel_idx[b*2+1];
    const float p0 = sel_probs[b*2+0], p1 = sel_probs[b*2+1];
    const int t = threadIdx.x;
    const int col = t & 127;
    const int gh  = t >> 7;
    const int o = nb * 128 + col;
    const float* w0 = W + (size_t)i0 * DM * DO + (size_t)(kt * 32) * DO + o;
    const float* w1 = W + (size_t)i1 * DM * DO + (size_t)(kt * 32) * DO + o;
    char* tile = (char*)wpack + ((size_t)((b * 8 + nb) * 32 + kt)) * 8192;
    const int q = (col >> 1) & 3;
    #pragma unroll
    for (int gg = 0; gg < 2; ++gg) {
        const int g = gh * 2 + gg;
        float v[8];
        #pragma unroll
        for (int j = 0; j < 8; ++j)
            v[j] = p0 * w0[(size_t)(g * 8 + j) * DO] + p1 * w1[(size_t)(g * 8 + j) * DO];
        uint4 u;
        u.x = pkbf(v[0], v[1]); u.y = pkbf(v[2], v[3]);
        u.z = pkbf(v[4], v[5]); u.w = pkbf(v[6], v[7]);
        *reinterpret_cast<uint4*>(tile + col * 64 + ((g ^ q) << 4)) = u;
    }
}

__global__ __launch_bounds__(256, 4) void gemm4(
    const float* __restrict__ X, const unsigned short* __restrict__ wpack,
    const float* __restrict__ beff, float* __restrict__ out)
{
    __shared__ char lds[32768];
    const int id = blockIdx.x;
    const int swz = (id & 7) * 256 + (id >> 3);
    const int b  = swz >> 8;
    const int bm = (swz >> 3) & 31;
    const int nb = swz & 7;
    const int t = threadIdx.x;
    const int wave = t >> 6, lane = t & 63;
    const int wm = wave >> 1, wn = wave & 1;
    const int fr = lane & 15, fq = lane >> 4;
    const int s_row = t >> 1;
    const int s_h   = t & 1;
    const float* xrow = X + ((size_t)(b * S_ + bm * 128 + s_row)) * DM + s_h * 16;
    const int sq = (s_row >> 1) & 3;
    const int wrA0 = s_row * 64 + (((s_h * 2 + 0) ^ sq) << 4);
    const int wrA1 = s_row * 64 + (((s_h * 2 + 1) ^ sq) << 4);
    const char* wtile = (const char*)wpack + ((size_t)((b * 8 + nb) * 32)) * 8192;
    const int axor = (fr >> 1) & 3;
    const int rdA = (wm * 64 + fr) * 64 + ((fq ^ axor) << 4);
    const int rdB = (wn * 64 + fr) * 64 + ((fq ^ axor) << 4);
    f32x4 acc[4][4] = {};
    float4 ax0, ax1, ax2, ax3;
#define LOAD_X(KT)                                                            \
    {   const float* s = xrow + (KT) * 32;                                    \
        ax0 = *reinterpret_cast<const float4*>(s);                            \
        ax1 = *reinterpret_cast<const float4*>(s + 4);                        \
        ax2 = *reinterpret_cast<const float4*>(s + 8);                        \
        ax3 = *reinterpret_cast<const float4*>(s + 12); }
#define STAGE_B(KT, BOFF)                                                     \
    {   const char* gB = wtile + (size_t)(KT) * 8192;                         \
        _Pragma("unroll")                                                     \
        for (int r = 0; r < 2; ++r)                                           \
            __builtin_amdgcn_global_load_lds(                                 \
                (const __attribute__((address_space(1))) void*)(gB + (wave*2+r)*1024 + lane*16), \
                (__attribute__((address_space(3))) void*)(lds + (BOFF) + (wave*2+r)*1024),       \
                16, 0, 0); }
#define WRITE_A(AOFF)                                                         \
    {   uint4 u0, u1;                                                         \
        u0.x = pkbf(ax0.x, ax0.y); u0.y = pkbf(ax0.z, ax0.w);                 \
        u0.z = pkbf(ax1.x, ax1.y); u0.w = pkbf(ax1.z, ax1.w);                 \
        u1.x = pkbf(ax2.x, ax2.y); u1.y = pkbf(ax2.z, ax2.w);                 \
        u1.z = pkbf(ax3.x, ax3.y); u1.w = pkbf(ax3.z, ax3.w);                 \
        *reinterpret_cast<uint4*>(lds + (AOFF) + wrA0) = u0;                  \
        *reinterpret_cast<uint4*>(lds + (AOFF) + wrA1) = u1; }
    LOAD_X(0);
    __builtin_amdgcn_sched_barrier(0);
    STAGE_B(0, 16384);
    __builtin_amdgcn_sched_barrier(0);
    WRITE_A(0);
    __syncthreads();
    for (int kt = 0; kt < 32; ++kt) {
        const int cur = (kt & 1) * 8192;
        const int nxt = 8192 - cur;
        if (kt < 31) {
            LOAD_X(kt + 1);
            __builtin_amdgcn_sched_barrier(0);
            STAGE_B(kt + 1, 16384 + nxt);
            __builtin_amdgcn_sched_barrier(0);
        }
        bf16x8 bf[4];
        #pragma unroll
        for (int nf = 0; nf < 4; ++nf)
            bf[nf] = *reinterpret_cast<const bf16x8*>(lds + 16384 + cur + rdB + nf * 1024);
        #pragma unroll
        for (int m = 0; m < 4; ++m) {
            bf16x8 af = *reinterpret_cast<const bf16x8*>(lds + cur + rdA + m * 1024);
            #pragma unroll
            for (int nf = 0; nf < 4; ++nf)
                acc[m][nf] = __builtin_amdgcn_mfma_f32_16x16x32_bf16(af, bf[nf], acc[m][nf], 0, 0, 0);
        }
        if (kt < 31) { WRITE_A(nxt); }
        __syncthreads();
    }
    const float* be = beff + (size_t)b * DO + nb * 128 + wn * 64;
    float bv[4];
    #pragma unroll
    for (int nf = 0; nf < 4; ++nf) bv[nf] = be[nf * 16 + fr];
    float* ob = out + ((size_t)(b * S_ + bm * 128 + wm * 64)) * DO + nb * 128 + wn * 64;
    #pragma unroll
    for (int m = 0; m < 4; ++m) {
        #pragma unroll
        for (int nf = 0; nf < 4; ++nf) {
            const int col = nf * 16 + fr;
            #pragma unroll
            for (int r = 0; r < 4; ++r) {
                const int row = m * 16 + fq * 4 + r;
                const float xv = acc[m][nf][r] + bv[nf];
                ob[(size_t)row * DO + col] = 1.0f / (1.0f + __expf(-xv));
            }
        }
    }
#undef LOAD_X
#undef STAGE_B
#undef WRITE_A
}

extern "C" void kernel_launch(void* const* d_in, const int* in_sizes, int n_in,
                              void* d_out, int out_size, void* d_ws, size_t ws_size,
                              hipStream_t stream) {
    const float* tensor    = (const float*)d_in[0];
    const int*   sel_idx   = (const int*)d_in[1];
    const float* sel_probs = (const float*)d_in[2];
    const float* W         = (const float*)d_in[3];
    const float* bias      = (const float*)d_in[4];
    float* out = (float*)d_out;

    const size_t XP = (size_t)2048 * 32768;          // 64 MiB xpack
    const size_t WP = (size_t)512 * 32768;           // 16 MiB wpack64
    const size_t NEED = XP + WP + (size_t)B_ * DO * 4;

    if (ws_size >= NEED) {
        unsigned short* xpack = (unsigned short*)d_ws;
        unsigned short* wpack = (unsigned short*)((char*)d_ws + XP);
        float* beff = (float*)((char*)d_ws + XP + WP);

        hipFuncSetAttribute((const void*)gemmx,
                            hipFuncAttributeMaxDynamicSharedMemorySize, 131072);

        hipLaunchKernelGGL(prep_xpack, dim3(16, 16, 8), dim3(256), 0, stream,
                           tensor, xpack);
        hipLaunchKernelGGL(prep_wpack64, dim3(16, 4, 8), dim3(256), 0, stream,
                           W, sel_idx, sel_probs, wpack);
        hipLaunchKernelGGL(prep_beff, dim3(8), dim3(256), 0, stream,
                           bias, sel_idx, sel_probs, beff);
        hipLaunchKernelGGL(gemmx, dim3(512), dim3(512), 131072, stream,
                           xpack, wpack, beff, out);
    } else {
        unsigned short* wpack = (unsigned short*)d_ws;                   // 16 MiB
        float* beff = (float*)((char*)d_ws + (size_t)8 * 8 * 32 * 8192);
        hipLaunchKernelGGL(prep_wpack_f, dim3(32, 8, 8), dim3(256), 0, stream,
                           W, sel_idx, sel_probs, wpack);
        hipLaunchKernelGGL(prep_beff, dim3(8), dim3(256), 0, stream,
                           bias, sel_idx, sel_probs, beff);
        hipLaunchKernelGGL(gemm4, dim3(2048), dim3(256), 0, stream,
                           tensor, wpack, beff, out);
    }
}